// Round 9
// baseline (272.152 us; speedup 1.0000x reference)
//
#include <hip/hip_runtime.h>
#include <hip/hip_fp16.h>

// GCN 2-layer. Pipeline:
//   blkhist -> rowscan -> topscan -> scatter2 -> bsort
//   -> gemm1 -> agg1 x4 (feature chunks) -> gemm2 -> agg2 x2
// R8 post-mortem: agg1 pinned on L2-miss fabric traffic (12.8 MB table vs
// 4 MB/XCD L2; FETCH 154 MB). This round: feature-chunked tables (3.2 MB
// per chunk, L2-resident) + one aggregation pass per chunk. Instruction
// count conserved (8 nodes/wave x 8 lanes). Per-feature math identical.

#define BSHIFT 8
#define BNODES 256
#define NB 256       // partition blocks
#define BSTRIDE 512  // blkcnt row stride

union H8 {  // 8 fp16 = 16 B (static-index use only! R6 lesson)
    uint4 u;
    __half2 h[4];
};

// Per-block bucket histogram: blkcnt[blk*BSTRIDE + bin].
__global__ __launch_bounds__(256) void blkhist_kernel(
    const int* __restrict__ dst, int E, int* __restrict__ blkcnt, int B) {
    __shared__ int h[512];
    int t = threadIdx.x, b = blockIdx.x;
    for (int i = t; i < 512; i += 256) h[i] = 0;
    __syncthreads();
    int per = (E + NB - 1) / NB;
    int lo = b * per;
    int hi = min(lo + per, E);
    for (int i = lo + t; i < hi; i += 256) atomicAdd(&h[dst[i] >> BSHIFT], 1);
    __syncthreads();
    for (int i = t; i < B; i += 256) blkcnt[b * BSTRIDE + i] = h[i];
}

// One block per bin: exclusive scan across NB block counts; emit bin total.
__global__ __launch_bounds__(256) void rowscan_kernel(
    int* __restrict__ blkcnt, int* __restrict__ rowtot) {
    __shared__ int s[NB];
    int t = threadIdx.x, bin = blockIdx.x;
    int v = blkcnt[t * BSTRIDE + bin];
    s[t] = v;
    __syncthreads();
#pragma unroll
    for (int d = 1; d < NB; d <<= 1) {
        int u = (t >= d) ? s[t - d] : 0;
        __syncthreads();
        s[t] += u;
        __syncthreads();
    }
    blkcnt[t * BSTRIDE + bin] = s[t] - v;
    if (t == NB - 1) rowtot[bin] = s[t];
}

// One block: exclusive scan of bin totals -> base[].
__global__ __launch_bounds__(512) void topscan_kernel(
    const int* __restrict__ rowtot, int* __restrict__ base,
    int* __restrict__ off, int B, int E, int N) {
    __shared__ int s[512];
    int t = threadIdx.x;
    int v0 = (t < B) ? rowtot[t] : 0;
    s[t] = v0;
    __syncthreads();
#pragma unroll
    for (int d = 1; d < 512; d <<= 1) {
        int v = (t >= d) ? s[t - d] : 0;
        __syncthreads();
        s[t] += v;
        __syncthreads();
    }
    if (t < B) base[t] = s[t] - v0;
    if (t == 0) {
        base[B] = E;
        off[N] = E;
    }
}

// Scatter via LDS cursors seeded from precomputed bases. No global atomics.
__global__ __launch_bounds__(256) void scatter2_kernel(
    const int* __restrict__ src, const int* __restrict__ dst,
    const int* __restrict__ blkcnt, const int* __restrict__ base,
    int* __restrict__ packed, int E, int B) {
    __shared__ int cur[512];
    int t = threadIdx.x, b = blockIdx.x;
    for (int i = t; i < B; i += 256) cur[i] = base[i] + blkcnt[b * BSTRIDE + i];
    __syncthreads();
    int per = (E + NB - 1) / NB;
    int lo = b * per;
    int hi = min(lo + per, E);
    for (int i = lo + t; i < hi; i += 256) {
        int d = dst[i];
        int pos = atomicAdd(&cur[d >> BSHIFT], 1);
        packed[pos] = (src[i] << BSHIFT) | (d & (BNODES - 1));
    }
}

// Per-bucket LDS counting sort -> ssrc grouped by node; also off & dinv.
__global__ __launch_bounds__(256) void bsort_kernel(
    const int* __restrict__ packed, const int* __restrict__ base,
    int* __restrict__ ssrc, int* __restrict__ off, float* __restrict__ dinv,
    int N) {
    __shared__ int s[BNODES];
    __shared__ int cur[BNODES];
    int t = threadIdx.x, b = blockIdx.x;
    s[t] = 0;
    __syncthreads();
    int lo = base[b], hi = base[b + 1];
    for (int i = lo + t; i < hi; i += 256)
        atomicAdd(&s[packed[i] & (BNODES - 1)], 1);
    __syncthreads();
    int deg = s[t];
    __syncthreads();
    s[t] = deg;
    __syncthreads();
#pragma unroll
    for (int d = 1; d < BNODES; d <<= 1) {
        int v = (t >= d) ? s[t - d] : 0;
        __syncthreads();
        s[t] += v;
        __syncthreads();
    }
    int excl = s[t] - deg;
    cur[t] = excl;
    int node = (b << BSHIFT) + t;
    if (node < N) {
        off[node] = lo + excl;
        dinv[node] = rsqrtf((float)(deg + 1));
    }
    __syncthreads();
    for (int i = lo + t; i < hi; i += 256) {
        int p = packed[i];
        int pos = atomicAdd(&cur[p & (BNODES - 1)], 1);
        ssrc[lo + pos] = p >> BSHIFT;
    }
}

// hs = (x@W1)*dinv -> fp16, CHUNKED layout hsC[c][node][16feats], c=0..3.
__global__ __launch_bounds__(256) void gemm1_kernel(
    const float* __restrict__ x, const float* __restrict__ W1,
    const float* __restrict__ dinv, __half* __restrict__ hsh, int N) {
    __shared__ float4 Ws[64 * 16];
    int t = threadIdx.x;
    const float4* W4 = (const float4*)W1;
    for (int i = t; i < 1024; i += 256) Ws[i] = W4[i];
    __syncthreads();
    int ra = blockIdx.x * 512 + t;
    int rb = ra + 256;
    if (ra >= N) return;
    bool hb = rb < N;
    const float4* xa = (const float4*)(x + (size_t)ra * 64);
    const float4* xb = (const float4*)(x + (size_t)rb * 64);
    float4 acc0[16], acc1[16];
#pragma unroll
    for (int j = 0; j < 16; j++) {
        acc0[j] = make_float4(0.f, 0.f, 0.f, 0.f);
        acc1[j] = make_float4(0.f, 0.f, 0.f, 0.f);
    }
    for (int k4 = 0; k4 < 16; k4++) {
        float4 x0 = xa[k4];
        float4 x1 = hb ? xb[k4] : make_float4(0.f, 0.f, 0.f, 0.f);
#pragma unroll
        for (int kk = 0; kk < 4; kk++) {
            float a0 = ((const float*)&x0)[kk];
            float a1 = ((const float*)&x1)[kk];
            const float4* wr = &Ws[(k4 * 4 + kk) * 16];
#pragma unroll
            for (int j = 0; j < 16; j++) {
                float4 w = wr[j];
                acc0[j].x += a0 * w.x; acc0[j].y += a0 * w.y;
                acc0[j].z += a0 * w.z; acc0[j].w += a0 * w.w;
                acc1[j].x += a1 * w.x; acc1[j].y += a1 * w.y;
                acc1[j].z += a1 * w.z; acc1[j].w += a1 * w.w;
            }
        }
    }
    float d0 = dinv[ra];
#pragma unroll
    for (int c = 0; c < 4; c++) {
        uint4* d4 = (uint4*)(hsh + ((size_t)c * N + ra) * 16);
        H8 p;
        float4 v0 = acc0[4 * c], v1 = acc0[4 * c + 1];
        p.h[0] = __floats2half2_rn(v0.x * d0, v0.y * d0);
        p.h[1] = __floats2half2_rn(v0.z * d0, v0.w * d0);
        p.h[2] = __floats2half2_rn(v1.x * d0, v1.y * d0);
        p.h[3] = __floats2half2_rn(v1.z * d0, v1.w * d0);
        d4[0] = p.u;
        float4 v2 = acc0[4 * c + 2], v3 = acc0[4 * c + 3];
        p.h[0] = __floats2half2_rn(v2.x * d0, v2.y * d0);
        p.h[1] = __floats2half2_rn(v2.z * d0, v2.w * d0);
        p.h[2] = __floats2half2_rn(v3.x * d0, v3.y * d0);
        p.h[3] = __floats2half2_rn(v3.z * d0, v3.w * d0);
        d4[1] = p.u;
    }
    if (hb) {
        float d1 = dinv[rb];
#pragma unroll
        for (int c = 0; c < 4; c++) {
            uint4* d4 = (uint4*)(hsh + ((size_t)c * N + rb) * 16);
            H8 p;
            float4 v0 = acc1[4 * c], v1 = acc1[4 * c + 1];
            p.h[0] = __floats2half2_rn(v0.x * d1, v0.y * d1);
            p.h[1] = __floats2half2_rn(v0.z * d1, v0.w * d1);
            p.h[2] = __floats2half2_rn(v1.x * d1, v1.y * d1);
            p.h[3] = __floats2half2_rn(v1.z * d1, v1.w * d1);
            d4[0] = p.u;
            float4 v2 = acc1[4 * c + 2], v3 = acc1[4 * c + 3];
            p.h[0] = __floats2half2_rn(v2.x * d1, v2.y * d1);
            p.h[1] = __floats2half2_rn(v2.z * d1, v2.w * d1);
            p.h[2] = __floats2half2_rn(v3.x * d1, v3.y * d1);
            p.h[3] = __floats2half2_rn(v3.z * d1, v3.w * d1);
            d4[1] = p.u;
        }
    }
}

// Layer-1 aggregate, ONE 16-feat chunk: 8 nodes/wave, 8 lanes/node (half2).
// Chunk table 3.2 MB -> L2-resident. hsC/h1C are chunk base pointers;
// b1c = b1 + 16*c.
__global__ __launch_bounds__(256) void agg1c_kernel(
    const __half2* __restrict__ hsC, const int* __restrict__ ssrc,
    const int* __restrict__ off, const float* __restrict__ dinv,
    const float* __restrict__ b1c, __half2* __restrict__ h1C, int N) {
    int lane = threadIdx.x & 63;
    int wid = (blockIdx.x * 256 + threadIdx.x) >> 6;
    int node = wid * 8 + (lane >> 3);
    int f2 = lane & 7;
    if (node >= N) return;
    float2 acc0 = __half22float2(hsC[(size_t)node * 8 + f2]);  // self-loop
    float2 acc1 = make_float2(0.f, 0.f);
    int lo = off[node], hi = off[node + 1];
    int e = lo;
    for (; e + 4 <= hi; e += 4) {
        int s0 = ssrc[e + 0], s1 = ssrc[e + 1];
        int s2 = ssrc[e + 2], s3 = ssrc[e + 3];
        float2 v0 = __half22float2(hsC[(size_t)s0 * 8 + f2]);
        float2 v1 = __half22float2(hsC[(size_t)s1 * 8 + f2]);
        float2 v2 = __half22float2(hsC[(size_t)s2 * 8 + f2]);
        float2 v3 = __half22float2(hsC[(size_t)s3 * 8 + f2]);
        acc0.x += v0.x + v1.x;
        acc0.y += v0.y + v1.y;
        acc1.x += v2.x + v3.x;
        acc1.y += v2.y + v3.y;
    }
    for (; e < hi; e++) {
        float2 v = __half22float2(hsC[(size_t)ssrc[e] * 8 + f2]);
        acc0.x += v.x;
        acc0.y += v.y;
    }
    float di = dinv[node];
    float2 bb = ((const float2*)b1c)[f2];
    float rx = fmaxf((acc0.x + acc1.x) * di + bb.x, 0.f);
    float ry = fmaxf((acc0.y + acc1.y) * di + bb.y, 0.f);
    h1C[(size_t)node * 8 + f2] = __floats2half2_rn(rx, ry);
}

// gs = (h1@W2)*dinv -> fp16, chunked gsC[c][node][16], c=0..1.
// Reads h1 in 4-chunk layout. Direct loads only (R6 lesson).
__global__ __launch_bounds__(256) void gemm2_kernel(
    const __half* __restrict__ h1h, const float* __restrict__ W2,
    const float* __restrict__ dinv, __half* __restrict__ gsh, int N) {
    __shared__ float4 Ws[64 * 8];
    int t = threadIdx.x;
    const float4* W4 = (const float4*)W2;
    for (int i = t; i < 512; i += 256) Ws[i] = W4[i];
    __syncthreads();
    int r = blockIdx.x * 256 + t;
    if (r >= N) return;
    float4 acc[8];
#pragma unroll
    for (int j = 0; j < 8; j++) acc[j] = make_float4(0.f, 0.f, 0.f, 0.f);
#pragma unroll
    for (int c = 0; c < 4; c++) {
        const __half2* xc = (const __half2*)(h1h + ((size_t)c * N + r) * 16);
#pragma unroll
        for (int k2 = 0; k2 < 8; k2++) {
            float2 f = __half22float2(xc[k2]);
            int k = c * 16 + 2 * k2;
            const float4* w0 = &Ws[k * 8];
            const float4* w1 = &Ws[(k + 1) * 8];
#pragma unroll
            for (int j = 0; j < 8; j++) {
                float4 wa = w0[j];
                acc[j].x += f.x * wa.x; acc[j].y += f.x * wa.y;
                acc[j].z += f.x * wa.z; acc[j].w += f.x * wa.w;
            }
#pragma unroll
            for (int j = 0; j < 8; j++) {
                float4 wb = w1[j];
                acc[j].x += f.y * wb.x; acc[j].y += f.y * wb.y;
                acc[j].z += f.y * wb.z; acc[j].w += f.y * wb.w;
            }
        }
    }
    float d0 = dinv[r];
#pragma unroll
    for (int c = 0; c < 2; c++) {
        uint4* g4 = (uint4*)(gsh + ((size_t)c * N + r) * 16);
        H8 p;
        float4 v0 = acc[4 * c], v1 = acc[4 * c + 1];
        p.h[0] = __floats2half2_rn(v0.x * d0, v0.y * d0);
        p.h[1] = __floats2half2_rn(v0.z * d0, v0.w * d0);
        p.h[2] = __floats2half2_rn(v1.x * d0, v1.y * d0);
        p.h[3] = __floats2half2_rn(v1.z * d0, v1.w * d0);
        g4[0] = p.u;
        float4 v2 = acc[4 * c + 2], v3 = acc[4 * c + 3];
        p.h[0] = __floats2half2_rn(v2.x * d0, v2.y * d0);
        p.h[1] = __floats2half2_rn(v2.z * d0, v2.w * d0);
        p.h[2] = __floats2half2_rn(v3.x * d0, v3.y * d0);
        p.h[3] = __floats2half2_rn(v3.z * d0, v3.w * d0);
        g4[1] = p.u;
    }
}

// Layer-2 aggregate, ONE 16-feat chunk: 8 nodes/wave, 8 lanes/node.
// outc = out + 16*c (fp32 row-major out); each node writes a full 64 B line.
__global__ __launch_bounds__(256) void agg2c_kernel(
    const __half2* __restrict__ gsC, const int* __restrict__ ssrc,
    const int* __restrict__ off, const float* __restrict__ dinv,
    const float* __restrict__ b2c, float* __restrict__ outc, int N) {
    int lane = threadIdx.x & 63;
    int wid = (blockIdx.x * 256 + threadIdx.x) >> 6;
    int node = wid * 8 + (lane >> 3);
    int f2 = lane & 7;
    if (node >= N) return;
    float2 acc0 = __half22float2(gsC[(size_t)node * 8 + f2]);  // self-loop
    float2 acc1 = make_float2(0.f, 0.f);
    int lo = off[node], hi = off[node + 1];
    int e = lo;
    for (; e + 4 <= hi; e += 4) {
        int s0 = ssrc[e + 0], s1 = ssrc[e + 1];
        int s2 = ssrc[e + 2], s3 = ssrc[e + 3];
        float2 v0 = __half22float2(gsC[(size_t)s0 * 8 + f2]);
        float2 v1 = __half22float2(gsC[(size_t)s1 * 8 + f2]);
        float2 v2 = __half22float2(gsC[(size_t)s2 * 8 + f2]);
        float2 v3 = __half22float2(gsC[(size_t)s3 * 8 + f2]);
        acc0.x += v0.x + v1.x;
        acc0.y += v0.y + v1.y;
        acc1.x += v2.x + v3.x;
        acc1.y += v2.y + v3.y;
    }
    for (; e < hi; e++) {
        float2 v = __half22float2(gsC[(size_t)ssrc[e] * 8 + f2]);
        acc0.x += v.x;
        acc0.y += v.y;
    }
    float di = dinv[node];
    float2 bb = ((const float2*)b2c)[f2];
    float2 r;
    r.x = (acc0.x + acc1.x) * di + bb.x;
    r.y = (acc0.y + acc1.y) * di + bb.y;
    *(float2*)(outc + (size_t)node * 32 + 2 * f2) = r;
}

extern "C" void kernel_launch(void* const* d_in, const int* in_sizes, int n_in,
                              void* d_out, int out_size, void* d_ws,
                              size_t ws_size, hipStream_t stream) {
    const float* x  = (const float*)d_in[0];
    const int* ei   = (const int*)d_in[1];
    const float* W1 = (const float*)d_in[2];
    const float* b1 = (const float*)d_in[3];
    const float* W2 = (const float*)d_in[4];
    const float* b2 = (const float*)d_in[5];
    int N = in_sizes[0] / 64;
    int E = in_sizes[1] / 2;
    const int* src = ei;
    const int* dst = ei + E;
    int B = (N + BNODES - 1) >> BSHIFT;  // 391 for N=100000

    char* ws = (char*)d_ws;
    size_t o = 0;
    auto align16 = [&o]() { o = (o + 15) & ~(size_t)15; };
    int* blkcnt  = (int*)(ws + o); o += (size_t)NB * BSTRIDE * 4; align16();
    int* rowtot  = (int*)(ws + o); o += 512 * 4; align16();
    int* base    = (int*)(ws + o); o += 513 * 4; align16();
    int* off     = (int*)(ws + o); o += ((size_t)N + 1) * 4; align16();
    float* dinv  = (float*)(ws + o); o += (size_t)N * 4; align16();
    int* packed  = (int*)(ws + o); o += (size_t)E * 4; align16();
    int* ssrc    = (int*)(ws + o); o += (size_t)E * 4; align16();
    __half* hsh  = (__half*)(ws + o); o += (size_t)N * 64 * 2; align16();
    __half* h1h  = (__half*)(ws + o); o += (size_t)N * 64 * 2; align16();
    __half* gsh  = hsh;  // hsh dead after agg1 passes; reuse (N*32 fp16)
    float* outp  = (float*)d_out;

    blkhist_kernel<<<NB, 256, 0, stream>>>(dst, E, blkcnt, B);
    rowscan_kernel<<<B, 256, 0, stream>>>(blkcnt, rowtot);
    topscan_kernel<<<1, 512, 0, stream>>>(rowtot, base, off, B, E, N);
    scatter2_kernel<<<NB, 256, 0, stream>>>(src, dst, blkcnt, base, packed, E,
                                            B);
    bsort_kernel<<<B, 256, 0, stream>>>(packed, base, ssrc, off, dinv, N);
    gemm1_kernel<<<(N + 511) / 512, 256, 0, stream>>>(x, W1, dinv, hsh, N);
    int wgrid = (int)(((size_t)((N + 7) / 8) * 64 + 255) / 256);
    for (int c = 0; c < 4; c++) {
        agg1c_kernel<<<wgrid, 256, 0, stream>>>(
            (const __half2*)(hsh + (size_t)c * N * 16), ssrc, off, dinv,
            b1 + 16 * c, (__half2*)(h1h + (size_t)c * N * 16), N);
    }
    gemm2_kernel<<<(N + 255) / 256, 256, 0, stream>>>(h1h, W2, dinv, gsh, N);
    for (int c = 0; c < 2; c++) {
        agg2c_kernel<<<wgrid, 256, 0, stream>>>(
            (const __half2*)(gsh + (size_t)c * N * 16), ssrc, off, dinv,
            b2 + 16 * c, outp + 16 * c, N);
    }
}